// Round 20
// baseline (131.161 us; speedup 1.0000x reference)
//
#include <hip/hip_runtime.h>
#include <math.h>
#include <stdint.h>

typedef float f32x4 __attribute__((ext_vector_type(4)));
typedef __bf16 bf16x8 __attribute__((ext_vector_type(8)));
typedef __bf16 bf16x4 __attribute__((ext_vector_type(4)));

constexpr int Bc = 2, Tc = 2048, Dc = 768, Hc = 12, Wc = 1024;
// 1/sqrt(64) * log2(e), folded into Wq at prep time
#define CEXP 0.18033688011112042f

__device__ __forceinline__ f32x4 mfma_bf16(bf16x8 a, bf16x8 b, f32x4 c) {
    return __builtin_amdgcn_mfma_f32_16x16x32_bf16(a, b, c, 0, 0, 0);
}
__device__ __forceinline__ void gload16(const void* g, void* l) {
    __builtin_amdgcn_global_load_lds(
        (const __attribute__((address_space(1))) uint32_t*)g,
        (__attribute__((address_space(3))) uint32_t*)l, 16, 0, 0);
}
__device__ __forceinline__ uint32_t pack2(float a, float b) {
    union { __bf16 h[2]; uint32_t u; } x;
    x.h[0] = (__bf16)a; x.h[1] = (__bf16)b; return x.u;
}
__device__ __forceinline__ void s_wait_vm4() { asm volatile("s_waitcnt vmcnt(4)" ::: "memory"); }
__device__ __forceinline__ void s_wait_vm3() { asm volatile("s_waitcnt vmcnt(3)" ::: "memory"); }
__device__ __forceinline__ void s_wait_vm2() { asm volatile("s_waitcnt vmcnt(2)" ::: "memory"); }
__device__ __forceinline__ void s_wait_vm0() { asm volatile("s_waitcnt vmcnt(0)" ::: "memory"); }
__device__ __forceinline__ void s_wait_lgkm0() { asm volatile("s_waitcnt lgkmcnt(0)" ::: "memory"); }
__device__ __forceinline__ void bar()        { __builtin_amdgcn_s_barrier(); }
// attn: 2 loads per staged tile
__device__ __forceinline__ void wait_tiles2(int infl) {
    if (infl >= 2) s_wait_vm4();
    else if (infl == 1) s_wait_vm2();
    else s_wait_vm0();
}

// ---------------- weight transpose prep (LDS-tiled) ----------------
__global__ __launch_bounds__(256) void k_prep_w(
    const float* __restrict__ Wq, const float* __restrict__ Wk,
    const float* __restrict__ Wv, const float* __restrict__ Wgq,
    const float* __restrict__ Wo, const float* __restrict__ Wro,
    __bf16* __restrict__ wTproj, __bf16* __restrict__ wTout)
{
    __shared__ __bf16 ldsT[64][66];
    const int wsel = blockIdx.y;
    const float* srcs[6] = {Wq, Wk, Wv, Wgq, Wo, Wro};
    const float* src = srcs[wsel];
    __bf16* dst; int dstride, koff;
    if (wsel < 4) { dst = wTproj + (size_t)wsel * Dc * Dc; dstride = Dc;  koff = 0; }
    else if (wsel == 4) { dst = wTout; dstride = 1536; koff = 0; }
    else { dst = wTout; dstride = 1536; koff = 768; }
    const float scale = (wsel == 0) ? CEXP : 1.0f;

    int tile = blockIdx.x;              // 144 = 12x12 tiles of 64x64
    int tk = tile % 12, tn = tile / 12;
    int k0 = tk * 64, n0 = tn * 64;
    int i = threadIdx.x, rsub = i >> 4, c4 = i & 15;
#pragma unroll
    for (int rep = 0; rep < 4; ++rep) {
        int row = rep * 16 + rsub;
        float4 v = *(const float4*)(src + (size_t)(k0 + row) * Dc + n0 + c4 * 4);
        ldsT[c4 * 4 + 0][row] = (__bf16)(v.x * scale);
        ldsT[c4 * 4 + 1][row] = (__bf16)(v.y * scale);
        ldsT[c4 * 4 + 2][row] = (__bf16)(v.z * scale);
        ldsT[c4 * 4 + 3][row] = (__bf16)(v.w * scale);
    }
    __syncthreads();
#pragma unroll
    for (int rep = 0; rep < 4; ++rep) {
        int n = rep * 16 + rsub;
        bf16x4 o = *(const bf16x4*)&ldsT[n][c4 * 4];
        *(bf16x4*)(dst + (size_t)(n0 + n) * dstride + koff + k0 + c4 * 4) = o;
    }
}

// stateT[b,h][v][k] = state[b,h][k][v]
__global__ __launch_bounds__(256) void k_prep_state(
    const float* __restrict__ st, __bf16* __restrict__ stT)
{
    int idx = blockIdx.x * 256 + threadIdx.x;
    int bh = idx >> 12, kk = (idx >> 6) & 63, vv = idx & 63;
    stT[(size_t)bh * 4096 + vv * 64 + kk] = (__bf16)st[idx];
}

// ---------------- fused RMSNorm + gate ----------------
__global__ __launch_bounds__(256) void k_norm_gate(
    const float* __restrict__ x, const float* __restrict__ norm_w,
    const float* __restrict__ Wg, const float* __restrict__ bg,
    __bf16* __restrict__ xnb, float* __restrict__ gmean)
{
    int row = blockIdx.x, tid = threadIdx.x;
    int wv = tid >> 6;
    const float* xr = x + (size_t)row * Dc;
    float4 v = make_float4(0.f, 0.f, 0.f, 0.f);
    float ss = 0.f;
    if (tid < 192) {
        v = ((const float4*)xr)[tid];
        ss = v.x * v.x + v.y * v.y + v.z * v.z + v.w * v.w;
    }
#pragma unroll
    for (int m = 32; m; m >>= 1) ss += __shfl_xor(ss, m, 64);
    __shared__ float red[4];
    __shared__ float pred[4][12];
    if ((tid & 63) == 0) red[wv] = ss;
    __syncthreads();
    float tot = red[0] + red[1] + red[2] + red[3];
    float rms = rsqrtf(tot * (1.f / 768.f) + 1e-6f);
    float xn0 = 0.f, xn1 = 0.f, xn2 = 0.f, xn3 = 0.f;
    if (tid < 192) {
        float4 nw = ((const float4*)norm_w)[tid];
        xn0 = v.x * rms * nw.x; xn1 = v.y * rms * nw.y;
        xn2 = v.z * rms * nw.z; xn3 = v.w * rms * nw.w;
        bf16x4 o;
        o[0] = (__bf16)xn0; o[1] = (__bf16)xn1; o[2] = (__bf16)xn2; o[3] = (__bf16)xn3;
        *(bf16x4*)(xnb + (size_t)row * Dc + tid * 4) = o;
    }
    float p[12];
#pragma unroll
    for (int h = 0; h < 12; ++h) p[h] = 0.f;
    if (tid < 192) {
        const float* wr = Wg + (size_t)tid * 48;   // 4 rows x 12
#pragma unroll
        for (int h = 0; h < 12; ++h)
            p[h] = xn0 * wr[h] + xn1 * wr[12 + h] + xn2 * wr[24 + h] + xn3 * wr[36 + h];
    }
#pragma unroll
    for (int h = 0; h < 12; ++h) {
#pragma unroll
        for (int m = 32; m; m >>= 1) p[h] += __shfl_xor(p[h], m, 64);
    }
    if ((tid & 63) == 0) {
#pragma unroll
        for (int h = 0; h < 12; ++h) pred[wv][h] = p[h];
    }
    __syncthreads();
    if (tid == 0) {
        float s = 0.f;
#pragma unroll
        for (int h = 0; h < 12; ++h) {
            float ph = pred[0][h] + pred[1][h] + pred[2][h] + pred[3][h];
            s += 1.f / (1.f + expf(-(ph + bg[h])));
        }
        gmean[row] = s * (1.f / 12.f);
    }
}

// ---------------- GEMM: 256-block balanced grid (1 block/CU) ----------------
// MODE 0: 128x384 tiles (32m x 8n = 256), BK=32; waves0-1 stage A (4/thr),
//         waves2-7 stage B (4/thr); wave tile 32x192 (MI=2,NI=12).
// MODE 1: 128x96 tiles (32m x 8n = 256), BK=64; waves0-3 stage A (4/thr),
//         waves4-7 stage B (3/thr); wave tile 32x48 (MI=2,NI=3).
template <int MODE>
__global__ __launch_bounds__(512, 2) void k_gemm(
    const __bf16* __restrict__ A, const __bf16* __restrict__ BT,
    const float* __restrict__ xres, float* __restrict__ outf,
    __bf16* __restrict__ qb, __bf16* __restrict__ kbf,
    __bf16* __restrict__ vtb, __bf16* __restrict__ qgb)
{
    constexpr int BM = 128;
    constexpr int BN = (MODE == 0) ? 384 : 96;
    constexpr int KD = (MODE == 0) ? 768 : 1536;
    constexpr int BK = (MODE == 0) ? 32 : 64;
    constexpr int KI = BK / 32;
    constexpr int MI = 2, NI = (MODE == 0) ? 12 : 3;
    constexpr int NK = KD / BK;                   // 24 both
    constexpr int WNW = (MODE == 0) ? 192 : 48;   // wave n-width
    __shared__ __bf16 As[2][BM * BK];
    __shared__ __bf16 Bs[2][BN * BK];
    const int tid = threadIdx.x, w = tid >> 6, lane = tid & 63;
    const int g = lane >> 4, t = lane & 15;
    int id = blockIdx.x, xcd = id & 7, l = id >> 3;   // l in [0,32)
    int m0, n0;
    if (MODE == 0) {
        m0 = (((xcd & 3) * 8) + (l & 7)) * BM;        // A slab 1.57MB
        n0 = (((xcd >> 2) * 4) + (l >> 3)) * BN;      // B slab 2.36MB
    } else {
        m0 = ((xcd * 4) + (l & 3)) * BM;              // A slab 1.57MB
        n0 = (l >> 2) * BN;                           // B full 2.36MB
    }
    const __bf16* Abase = A + (size_t)m0 * KD;
    const __bf16* Bbase = BT + (size_t)n0 * KD;
    const int wrow = (w >> 1) * 32, wcol = (w & 1) * WNW;
    const bool isA = (tid < 256);                 // only used for MODE 1 waits

    auto STAGE = [&](int buf, int k0) {
        if (MODE == 0) {
            if (tid < 128) {
#pragma unroll
                for (int c = 0; c < 4; ++c) {      // 512 A-granules (GR=4)
                    int chunk = c * 128 + tid, row = chunk >> 2, cix = chunk & 3;
                    gload16(Abase + (size_t)row * KD + k0 + cix * 8, &As[buf][chunk * 8]);
                }
            } else {
                int bi = tid - 128;
#pragma unroll
                for (int c = 0; c < 4; ++c) {      // 1536 B-granules
                    int chunk = c * 384 + bi, row = chunk >> 2, cix = chunk & 3;
                    gload16(Bbase + (size_t)row * KD + k0 + cix * 8, &Bs[buf][chunk * 8]);
                }
            }
        } else {
            if (tid < 256) {
#pragma unroll
                for (int c = 0; c < 4; ++c) {      // 1024 A-granules (GR=8)
                    int chunk = c * 256 + tid, row = chunk >> 3, cix = chunk & 7;
                    gload16(Abase + (size_t)row * KD + k0 + cix * 8, &As[buf][chunk * 8]);
                }
            } else {
                int bi = tid - 256;
#pragma unroll
                for (int c = 0; c < 3; ++c) {      // 768 B-granules
                    int chunk = c * 256 + bi, row = chunk >> 3, cix = chunk & 7;
                    gload16(Bbase + (size_t)row * KD + k0 + cix * 8, &Bs[buf][chunk * 8]);
                }
            }
        }
    };

    f32x4 acc[MI][NI] = {};
    STAGE(0, 0);
    STAGE(1, BK);
    for (int ks = 0; ks < NK; ++ks) {
        if (ks == NK - 1) s_wait_vm0();
        else if (MODE == 0) s_wait_vm4();         // uniform 4 loads/thr/tile
        else if (isA) s_wait_vm4();
        else s_wait_vm3();
        bar();
        const __bf16* Ab = As[ks & 1];
        const __bf16* Bb = Bs[ks & 1];
        bf16x8 af[MI][KI], bfr[NI][KI];
#pragma unroll
        for (int kk = 0; kk < KI; ++kk) {
#pragma unroll
            for (int mi = 0; mi < MI; ++mi)
                af[mi][kk] = *(const bf16x8*)(Ab + (wrow + mi * 16 + t) * BK + kk * 32 + g * 8);
#pragma unroll
            for (int ni = 0; ni < NI; ++ni)
                bfr[ni][kk] = *(const bf16x8*)(Bb + (wcol + ni * 16 + t) * BK + kk * 32 + g * 8);
        }
        s_wait_lgkm0();
        __builtin_amdgcn_sched_barrier(0);
        bar();                                    // all waves done reading buf
        if (ks + 2 < NK) STAGE(ks & 1, (ks + 2) * BK);
        __builtin_amdgcn_s_setprio(1);
#pragma unroll
        for (int kk = 0; kk < KI; ++kk)
#pragma unroll
            for (int mi = 0; mi < MI; ++mi)
#pragma unroll
                for (int ni = 0; ni < NI; ++ni)
                    acc[mi][ni] = mfma_bf16(af[mi][kk], bfr[ni][kk], acc[mi][ni]);
        __builtin_amdgcn_s_setprio(0);
    }
#pragma unroll
    for (int mi = 0; mi < MI; ++mi)
#pragma unroll
        for (int ni = 0; ni < NI; ++ni) {
            if (MODE == 1) {
#pragma unroll
                for (int r = 0; r < 4; ++r) {
                    int grow = m0 + wrow + mi * 16 + g * 4 + r;
                    int gcol = n0 + wcol + ni * 16 + t;
                    size_t idx = (size_t)grow * Dc + gcol;
                    outf[idx] = xres[idx] + acc[mi][ni][r];
                }
            } else {
                int coln = n0 + wcol + ni * 16;        // 16-aligned, single region
                int region = coln / 768;
                int cb = coln - region * 768;
                if (region == 2) {
                    // v^T: rho preserves r bits -> one aligned bf16x4 store
                    int grow0 = m0 + wrow + mi * 16 + g * 4;
                    int b = grow0 >> 11, ti0 = grow0 & (Tc - 1);
                    int c = cb + t;
                    int h = c >> 6, kd = c & 63;
                    int kap = ti0 & 63;
                    int rho = (kap & 32) | (((kap >> 2) & 3) << 3) | (((kap >> 4) & 1) << 2);
                    int ts = (ti0 & ~63) | (rho ^ ((kd & 7) << 3));
                    bf16x4 o;
                    o[0] = (__bf16)acc[mi][ni][0]; o[1] = (__bf16)acc[mi][ni][1];
                    o[2] = (__bf16)acc[mi][ni][2]; o[3] = (__bf16)acc[mi][ni][3];
                    *(bf16x4*)(vtb + ((size_t)(b * Hc + h) * 64 + kd) * Tc + ts) = o;
                } else {
#pragma unroll
                    for (int r = 0; r < 4; ++r) {
                        int grow = m0 + wrow + mi * 16 + g * 4 + r;
                        int b = grow >> 11, ti = grow & (Tc - 1);
                        int c = cb + t;
                        int h = c >> 6, kd = c & 63;
                        float v = acc[mi][ni][r];
                        if (region == 0)
                            qb[((size_t)(b * Hc + h) * Tc + ti) * 64 + kd] = (__bf16)v;
                        else if (region == 1) {
                            int kds = kd ^ ((ti & 7) << 3);
                            kbf[((size_t)(b * Hc + h) * Tc + ti) * 64 + kds] = (__bf16)v;
                        } else
                            qgb[((size_t)(b * Hc + h) * Tc + ti) * 64 + kd] = (__bf16)fmaxf(v, 0.f);
                    }
                }
            }
        }
}

// ---------------- sliding-window attention + fused GDN retrieval (R18) ----------------
__global__ __launch_bounds__(512, 6) void k_attn(
    const __bf16* __restrict__ q, const __bf16* __restrict__ k,
    const __bf16* __restrict__ vt, const __bf16* __restrict__ qg,
    const __bf16* __restrict__ stateT, const float* __restrict__ gmean,
    __bf16* __restrict__ ac)
{
    __shared__ __bf16 Ks[3][64 * 64];
    __shared__ __bf16 Vs[3][64 * 64];
    int id = blockIdx.x, xcd = id & 7, l = id >> 3;
    int nid = xcd * 96 + l;
    int sblk = nid & 31, h = (nid >> 5) % Hc, b = nid / (32 * Hc);
    int tid = threadIdx.x;
    int w = tid >> 6, lane = tid & 63;
    int g = lane >> 4, t = lane & 15;
    int q0 = sblk * 64, qw = q0 + (w & 3) * 16;
    const int myPar = w >> 2;
    const __bf16* qb = q + (size_t)(b * Hc + h) * Tc * 64;
    const __bf16* kb = k + (size_t)(b * Hc + h) * Tc * 64;
    const __bf16* vb = vt + (size_t)(b * Hc + h) * 64 * Tc;

    bf16x8 qf0 = *(const bf16x8*)(qb + (size_t)(qw + t) * 64 + g * 8);
    bf16x8 qf1 = *(const bf16x8*)(qb + (size_t)(qw + t) * 64 + 32 + g * 8);

    const int qi = qw + t;
    const int lowB = qi - Wc;
    const int xr = t & 7;

    f32x4 oacc[4] = {};
    float lsum = 0.f;

    const int s_begin = (q0 >= Wc) ? q0 - Wc : 0;
    const int NT = (q0 + 64 - s_begin) >> 6;

    auto STAGE = [&](int buf, int s0) {
        int ch = tid;
        gload16(kb + (size_t)(s0 + (ch >> 3)) * 64 + (ch & 7) * 8, &Ks[buf][ch * 8]);
        gload16(vb + (size_t)(ch >> 3) * Tc + s0 + (ch & 7) * 8, &Vs[buf][ch * 8]);
    };

    STAGE(0, s_begin);
    if (NT > 1) STAGE(1, s_begin + 64);
    if (NT > 2) STAGE(2, s_begin + 128);
    int buf = 0;
    for (int it = 0; it < NT; ++it) {
        int s0 = s_begin + it * 64;
        wait_tiles2(NT - 1 - it);
        bar();
        if ((it & 1) == myPar) {
            const __bf16* Kt = Ks[buf];
            const __bf16* Vt = Vs[buf];
            f32x4 sc[4];
            __builtin_amdgcn_s_setprio(1);
#pragma unroll
            for (int sub = 0; sub < 4; ++sub) {
                const __bf16* kr = Kt + (sub * 16 + t) * 64;
                bf16x8 kA = *(const bf16x8*)(kr + ((g ^ xr) << 3));
                bf16x8 kB = *(const bf16x8*)(kr + (((g + 4) ^ xr) << 3));
                f32x4 s = {};
                s = mfma_bf16(kA, qf0, s);
                s = mfma_bf16(kB, qf1, s);
                sc[sub] = s;
            }
            __builtin_amdgcn_s_setprio(0);
            float pv[4][4];
            bool fullT = (s0 + 63 <= qw) && (s0 >= qw + 15 - Wc);
            if (fullT) {
#pragma unroll
                for (int sub = 0; sub < 4; ++sub)
#pragma unroll
                    for (int r = 0; r < 4; ++r) {
                        float e = exp2f(sc[sub][r]);
                        pv[sub][r] = e;
                        lsum += e;
                    }
            } else {
#pragma unroll
                for (int sub = 0; sub < 4; ++sub)
#pragma unroll
                    for (int r = 0; r < 4; ++r) {
                        int kk = s0 + sub * 16 + g * 4 + r;
                        float e = exp2f(sc[sub][r]);
                        float val = (kk <= qi && kk >= lowB) ? e : 0.f;
                        pv[sub][r] = val;
                        lsum += val;
                    }
            }
            __builtin_amdgcn_s_setprio(1);
#pragma unroll
            for (int ks = 0; ks < 2; ++ks) {
                union { uint32_t u[4]; bf16x8 v; } pf;
                pf.u[0] = pack2(pv[ks * 2][0], pv[ks * 2][1]);
                pf.u[1] = pack2(pv[ks * 2][2], pv[ks * 2][3]);
                pf.u[2] = pack2(pv[ks * 2 + 1][0], pv[ks * 2 + 1][1]);
                pf.u[3] = pack2(pv[ks * 2 + 1][2], pv[ks * 2 + 1][3]);
#pragma unroll
                for (int n = 0; n < 4; ++n) {
                    const __bf16* vrow = Vt + (n * 16 + t) * 64;
                    bf16x8 vf = *(const bf16x8*)(vrow + ((((ks * 4) + g) ^ xr) << 3));
                    oacc[n] = mfma_bf16(pf.v, vf, oacc[n]);
                }
            }
            __builtin_amdgcn_s_setprio(0);
        }
        s_wait_lgkm0();
        __builtin_amdgcn_sched_barrier(0);
        bar();
        if (it + 3 < NT) STAGE(buf, s0 + 192);
        buf = (buf == 2) ? 0 : buf + 1;
    }
    float* cb = (float*)&Ks[0][0];
    if (w >= 4) {
        float* dst = cb + ((size_t)((w - 4) * 64 + lane)) * 20;
#pragma unroll
        for (int n = 0; n < 4; ++n) *(f32x4*)(dst + n * 4) = oacc[n];
        dst[16] = lsum;
    }
    bar();
    if (w < 4) {
        const float* src = cb + ((size_t)(w * 64 + lane)) * 20;
#pragma unroll
        for (int n = 0; n < 4; ++n) oacc[n] += *(const f32x4*)(src + n * 4);
        lsum += src[16];
        lsum += __shfl_xor(lsum, 16, 64);
        lsum += __shfl_xor(lsum, 32, 64);
        float linv = 1.f / lsum;
        float lq[4];
#pragma unroll
        for (int r = 0; r < 4; ++r) lq[r] = __shfl(linv, g * 4 + r, 64);
#pragma unroll
        for (int n = 0; n < 4; ++n)
#pragma unroll
            for (int r = 0; r < 4; ++r) {
                int qrow = qw + g * 4 + r;
                ac[(size_t)(b * Tc + qrow) * 1536 + h * 64 + n * 16 + t] =
                    (__bf16)(oacc[n][r] * lq[r]);
            }
        const __bf16* qgp = qg + (size_t)(b * Hc + h) * Tc * 64;
        const __bf16* sb = stateT + (size_t)(b * Hc + h) * 4096;
        bf16x8 a0 = *(const bf16x8*)(qgp + (size_t)(qw + t) * 64 + g * 8);
        bf16x8 a1 = *(const bf16x8*)(qgp + (size_t)(qw + t) * 64 + 32 + g * 8);
#pragma unroll
        for (int n = 0; n < 4; ++n) {
            bf16x8 b0 = *(const bf16x8*)(sb + (n * 16 + t) * 64 + g * 8);
            bf16x8 b1 = *(const bf16x8*)(sb + (n * 16 + t) * 64 + 32 + g * 8);
            f32x4 acc2 = {};
            acc2 = mfma_bf16(a0, b0, acc2);
            acc2 = mfma_bf16(a1, b1, acc2);
#pragma unroll
            for (int r = 0; r < 4; ++r) {
                int ti = qw + g * 4 + r;
                float gm = gmean[b * Tc + ti];
                ac[(size_t)(b * Tc + ti) * 1536 + 768 + h * 64 + n * 16 + t] =
                    (__bf16)(acc2[r] * gm);
            }
        }
    }
}

// ---------------- host ----------------
extern "C" void kernel_launch(void* const* d_in, const int* in_sizes, int n_in,
                              void* d_out, int out_size, void* d_ws, size_t ws_size,
                              hipStream_t stream) {
    (void)in_sizes; (void)n_in; (void)out_size; (void)ws_size;
    const float* x     = (const float*)d_in[0];
    const float* gdn   = (const float*)d_in[1];
    const float* Wq    = (const float*)d_in[2];
    const float* Wk    = (const float*)d_in[3];
    const float* Wv    = (const float*)d_in[4];
    const float* Wo    = (const float*)d_in[5];
    const float* Wgq   = (const float*)d_in[6];
    const float* Wro   = (const float*)d_in[7];
    const float* Wg    = (const float*)d_in[8];
    const float* bg    = (const float*)d_in[9];
    const float* normw = (const float*)d_in[10];
    float* out = (float*)d_out;

    char* p = (char*)d_ws;
    auto alloc = [&](size_t bytes) -> char* {
        char* r = p; p += (bytes + 255) & ~(size_t)255; return r;
    };
    constexpr size_t NROW = (size_t)Bc * Tc;          // 4096
    __bf16* xnb    = (__bf16*)alloc(NROW * Dc * 2);
    __bf16* wTproj = (__bf16*)alloc((size_t)4 * Dc * Dc * 2);   // 3072 x 768
    __bf16* wTout  = (__bf16*)alloc((size_t)Dc * 1536 * 2);     // 768 x 1536
    __bf16* stT    = (__bf16*)alloc((size_t)Bc * Hc * 64 * 64 * 2);
    __bf16* qbuf   = (__bf16*)alloc(NROW * Dc * 2);
    __bf16* kbuf   = (__bf16*)alloc(NROW * Dc * 2);
    __bf16* qgbuf  = (__bf16*)alloc(NROW * Dc * 2);
    __bf16* vtbuf  = (__bf16*)alloc(NROW * Dc * 2);
    __bf16* ac     = (__bf16*)alloc(NROW * 1536 * 2);           // [local | retr]
    float*  gmean  = (float*)alloc(NROW * 4);

    k_prep_w<<<dim3(144, 6), 256, 0, stream>>>(Wq, Wk, Wv, Wgq, Wo, Wro, wTproj, wTout);
    k_prep_state<<<(Bc * Hc * 64 * 64) / 256, 256, 0, stream>>>(gdn, stT);
    k_norm_gate<<<NROW, 256, 0, stream>>>(x, normw, Wg, bg, xnb, gmean);

    k_gemm<0><<<256, 512, 0, stream>>>(xnb, wTproj, nullptr, nullptr,
                                       qbuf, kbuf, vtbuf, qgbuf);
    k_attn<<<768, 512, 0, stream>>>(qbuf, kbuf, vtbuf, qgbuf, stT, gmean, ac);
    k_gemm<1><<<256, 512, 0, stream>>>(ac, wTout, x, out,
                                       nullptr, nullptr, nullptr, nullptr);
}

// Round 21
// 114.865 us; speedup vs baseline: 1.1419x; 1.1419x over previous
//
#include <hip/hip_runtime.h>
#include <math.h>
#include <stdint.h>

typedef float f32x4 __attribute__((ext_vector_type(4)));
typedef __bf16 bf16x8 __attribute__((ext_vector_type(8)));
typedef __bf16 bf16x4 __attribute__((ext_vector_type(4)));

constexpr int Bc = 2, Tc = 2048, Dc = 768, Hc = 12, Wc = 1024;
// 1/sqrt(64) * log2(e), folded into Wq at prep time
#define CEXP 0.18033688011112042f

__device__ __forceinline__ f32x4 mfma_bf16(bf16x8 a, bf16x8 b, f32x4 c) {
    return __builtin_amdgcn_mfma_f32_16x16x32_bf16(a, b, c, 0, 0, 0);
}
__device__ __forceinline__ void gload16(const void* g, void* l) {
    __builtin_amdgcn_global_load_lds(
        (const __attribute__((address_space(1))) uint32_t*)g,
        (__attribute__((address_space(3))) uint32_t*)l, 16, 0, 0);
}
__device__ __forceinline__ uint32_t pack2(float a, float b) {
    union { __bf16 h[2]; uint32_t u; } x;
    x.h[0] = (__bf16)a; x.h[1] = (__bf16)b; return x.u;
}
__device__ __forceinline__ void s_wait_vm4() { asm volatile("s_waitcnt vmcnt(4)" ::: "memory"); }
__device__ __forceinline__ void s_wait_vm2() { asm volatile("s_waitcnt vmcnt(2)" ::: "memory"); }
__device__ __forceinline__ void s_wait_vm0() { asm volatile("s_waitcnt vmcnt(0)" ::: "memory"); }
__device__ __forceinline__ void s_wait_lgkm0() { asm volatile("s_waitcnt lgkmcnt(0)" ::: "memory"); }
__device__ __forceinline__ void bar()        { __builtin_amdgcn_s_barrier(); }
// attn: 2 loads per staged tile
__device__ __forceinline__ void wait_tiles2(int infl) {
    if (infl >= 2) s_wait_vm4();
    else if (infl == 1) s_wait_vm2();
    else s_wait_vm0();
}

// ---------------- weight transpose prep (LDS-tiled) ----------------
__global__ __launch_bounds__(256) void k_prep_w(
    const float* __restrict__ Wq, const float* __restrict__ Wk,
    const float* __restrict__ Wv, const float* __restrict__ Wgq,
    const float* __restrict__ Wo, const float* __restrict__ Wro,
    __bf16* __restrict__ wTproj, __bf16* __restrict__ wTout)
{
    __shared__ __bf16 ldsT[64][66];
    const int wsel = blockIdx.y;
    const float* srcs[6] = {Wq, Wk, Wv, Wgq, Wo, Wro};
    const float* src = srcs[wsel];
    __bf16* dst; int dstride, koff;
    if (wsel < 4) { dst = wTproj + (size_t)wsel * Dc * Dc; dstride = Dc;  koff = 0; }
    else if (wsel == 4) { dst = wTout; dstride = 1536; koff = 0; }
    else { dst = wTout; dstride = 1536; koff = 768; }
    const float scale = (wsel == 0) ? CEXP : 1.0f;

    int tile = blockIdx.x;              // 144 = 12x12 tiles of 64x64
    int tk = tile % 12, tn = tile / 12;
    int k0 = tk * 64, n0 = tn * 64;
    int i = threadIdx.x, rsub = i >> 4, c4 = i & 15;
#pragma unroll
    for (int rep = 0; rep < 4; ++rep) {
        int row = rep * 16 + rsub;
        float4 v = *(const float4*)(src + (size_t)(k0 + row) * Dc + n0 + c4 * 4);
        ldsT[c4 * 4 + 0][row] = (__bf16)(v.x * scale);
        ldsT[c4 * 4 + 1][row] = (__bf16)(v.y * scale);
        ldsT[c4 * 4 + 2][row] = (__bf16)(v.z * scale);
        ldsT[c4 * 4 + 3][row] = (__bf16)(v.w * scale);
    }
    __syncthreads();
#pragma unroll
    for (int rep = 0; rep < 4; ++rep) {
        int n = rep * 16 + rsub;
        bf16x4 o = *(const bf16x4*)&ldsT[n][c4 * 4];
        *(bf16x4*)(dst + (size_t)(n0 + n) * dstride + koff + k0 + c4 * 4) = o;
    }
}

// stateT[b,h][v][k] = state[b,h][k][v]
__global__ __launch_bounds__(256) void k_prep_state(
    const float* __restrict__ st, __bf16* __restrict__ stT)
{
    int idx = blockIdx.x * 256 + threadIdx.x;
    int bh = idx >> 12, kk = (idx >> 6) & 63, vv = idx & 63;
    stT[(size_t)bh * 4096 + vv * 64 + kk] = (__bf16)st[idx];
}

// ---------------- fused RMSNorm + gate ----------------
__global__ __launch_bounds__(256) void k_norm_gate(
    const float* __restrict__ x, const float* __restrict__ norm_w,
    const float* __restrict__ Wg, const float* __restrict__ bg,
    __bf16* __restrict__ xnb, float* __restrict__ gmean)
{
    int row = blockIdx.x, tid = threadIdx.x;
    int wv = tid >> 6;
    const float* xr = x + (size_t)row * Dc;
    float4 v = make_float4(0.f, 0.f, 0.f, 0.f);
    float ss = 0.f;
    if (tid < 192) {
        v = ((const float4*)xr)[tid];
        ss = v.x * v.x + v.y * v.y + v.z * v.z + v.w * v.w;
    }
#pragma unroll
    for (int m = 32; m; m >>= 1) ss += __shfl_xor(ss, m, 64);
    __shared__ float red[4];
    __shared__ float pred[4][12];
    if ((tid & 63) == 0) red[wv] = ss;
    __syncthreads();
    float tot = red[0] + red[1] + red[2] + red[3];
    float rms = rsqrtf(tot * (1.f / 768.f) + 1e-6f);
    float xn0 = 0.f, xn1 = 0.f, xn2 = 0.f, xn3 = 0.f;
    if (tid < 192) {
        float4 nw = ((const float4*)norm_w)[tid];
        xn0 = v.x * rms * nw.x; xn1 = v.y * rms * nw.y;
        xn2 = v.z * rms * nw.z; xn3 = v.w * rms * nw.w;
        bf16x4 o;
        o[0] = (__bf16)xn0; o[1] = (__bf16)xn1; o[2] = (__bf16)xn2; o[3] = (__bf16)xn3;
        *(bf16x4*)(xnb + (size_t)row * Dc + tid * 4) = o;
    }
    float p[12];
#pragma unroll
    for (int h = 0; h < 12; ++h) p[h] = 0.f;
    if (tid < 192) {
        const float* wr = Wg + (size_t)tid * 48;   // 4 rows x 12
#pragma unroll
        for (int h = 0; h < 12; ++h)
            p[h] = xn0 * wr[h] + xn1 * wr[12 + h] + xn2 * wr[24 + h] + xn3 * wr[36 + h];
    }
#pragma unroll
    for (int h = 0; h < 12; ++h) {
#pragma unroll
        for (int m = 32; m; m >>= 1) p[h] += __shfl_xor(p[h], m, 64);
    }
    if ((tid & 63) == 0) {
#pragma unroll
        for (int h = 0; h < 12; ++h) pred[wv][h] = p[h];
    }
    __syncthreads();
    if (tid == 0) {
        float s = 0.f;
#pragma unroll
        for (int h = 0; h < 12; ++h) {
            float ph = pred[0][h] + pred[1][h] + pred[2][h] + pred[3][h];
            s += 1.f / (1.f + expf(-(ph + bg[h])));
        }
        gmean[row] = s * (1.f / 12.f);
    }
}

// ---------------- LDS-staged GEMM (R15) + L2-local XCD mapping ----------------
template <int MODE>
__global__ __launch_bounds__(256) void k_gemm(
    const __bf16* __restrict__ A, const __bf16* __restrict__ BT,
    const float* __restrict__ xres, float* __restrict__ outf,
    __bf16* __restrict__ qb, __bf16* __restrict__ kbf,
    __bf16* __restrict__ vtb, __bf16* __restrict__ qgb)
{
    constexpr int BM = (MODE == 0) ? 128 : 64;
    constexpr int BN = (MODE == 0) ? 128 : 64;
    constexpr int KD = (MODE == 0) ? 768 : 1536;
    constexpr int BK = (MODE == 0) ? 32 : 64;
    constexpr int KI = BK / 32;
    constexpr int WM = BM / 2, WN = BN / 2;
    constexpr int MI = WM / 16, NI = WN / 16;
    constexpr int NK = KD / BK;                   // 24 for both modes
    constexpr int GR = BK / 8;                    // 16B granules per row
    constexpr int ACH = BM * BK / 2048;           // gload chunks per thread (=2)
    constexpr int BCH = BN * BK / 2048;           // (=2)  -> 4 loads/thread/tile
    __shared__ __bf16 As[2][BM * BK];
    __shared__ __bf16 Bs[2][BN * BK];
    const int tid = threadIdx.x, w = tid >> 6, lane = tid & 63;
    const int g = lane >> 4, t = lane & 15;
    int id = blockIdx.x, xcd = id & 7, l = id >> 3;   // l in [0,96)
    int m0, n0;
    if (MODE == 0) {
        m0 = (((xcd & 3) * 8) + (l & 7)) * BM;
        n0 = (((xcd >> 2) * 12) + (l >> 3)) * BN;
    } else {
        m0 = ((xcd * 8) + (l & 7)) * BM;
        n0 = (l >> 3) * BN;
    }
    const __bf16* Abase = A + (size_t)m0 * KD;
    const __bf16* Bbase = BT + (size_t)n0 * KD;
    const int wrow = (w >> 1) * WM, wcol = (w & 1) * WN;

    auto STAGE = [&](int buf, int k0) {
#pragma unroll
        for (int c = 0; c < ACH; ++c) {
            int chunk = c * 256 + tid, row = chunk / GR, cix = chunk % GR;
            gload16(Abase + (size_t)row * KD + k0 + cix * 8, &As[buf][chunk * 8]);
        }
#pragma unroll
        for (int c = 0; c < BCH; ++c) {
            int chunk = c * 256 + tid, row = chunk / GR, cix = chunk % GR;
            gload16(Bbase + (size_t)row * KD + k0 + cix * 8, &Bs[buf][chunk * 8]);
        }
    };

    f32x4 acc[MI][NI] = {};
    STAGE(0, 0);
    STAGE(1, BK);
    for (int ks = 0; ks < NK; ++ks) {
        if (ks == NK - 1) s_wait_vm0(); else s_wait_vm4();   // counted, never drains early
        bar();
        const __bf16* Ab = As[ks & 1];
        const __bf16* Bb = Bs[ks & 1];
        bf16x8 af[MI][KI], bfr[NI][KI];
#pragma unroll
        for (int kk = 0; kk < KI; ++kk) {
#pragma unroll
            for (int mi = 0; mi < MI; ++mi)
                af[mi][kk] = *(const bf16x8*)(Ab + (wrow + mi * 16 + t) * BK + kk * 32 + g * 8);
#pragma unroll
            for (int ni = 0; ni < NI; ++ni)
                bfr[ni][kk] = *(const bf16x8*)(Bb + (wcol + ni * 16 + t) * BK + kk * 32 + g * 8);
        }
        s_wait_lgkm0();
        __builtin_amdgcn_sched_barrier(0);
        bar();                                   // all waves done reading buf
        if (ks + 2 < NK) STAGE(ks & 1, (ks + 2) * BK);
        __builtin_amdgcn_s_setprio(1);
#pragma unroll
        for (int kk = 0; kk < KI; ++kk)
#pragma unroll
            for (int mi = 0; mi < MI; ++mi)
#pragma unroll
                for (int ni = 0; ni < NI; ++ni)
                    acc[mi][ni] = mfma_bf16(af[mi][kk], bfr[ni][kk], acc[mi][ni]);
        __builtin_amdgcn_s_setprio(0);
    }
    const int region = (MODE == 0) ? (n0 / 768) : 0;
    if (MODE == 0 && region == 2) {
        // v^T region: rho preserves r in bits 0-1 -> pack one aligned bf16x4 store
#pragma unroll
        for (int mi = 0; mi < MI; ++mi)
#pragma unroll
            for (int ni = 0; ni < NI; ++ni) {
                int grow0 = m0 + wrow + mi * 16 + g * 4;
                int b = grow0 >> 11, ti0 = grow0 & (Tc - 1);
                int c = (n0 + wcol + ni * 16 + t) - 1536;
                int h = c >> 6, kd = c & 63;
                int kap = ti0 & 63;          // multiple of 4
                int rho = (kap & 32) | (((kap >> 2) & 3) << 3) | (((kap >> 4) & 1) << 2);
                int ts = (ti0 & ~63) | (rho ^ ((kd & 7) << 3));
                bf16x4 o;
                o[0] = (__bf16)acc[mi][ni][0]; o[1] = (__bf16)acc[mi][ni][1];
                o[2] = (__bf16)acc[mi][ni][2]; o[3] = (__bf16)acc[mi][ni][3];
                *(bf16x4*)(vtb + ((size_t)(b * Hc + h) * 64 + kd) * Tc + ts) = o;
            }
    } else {
#pragma unroll
        for (int mi = 0; mi < MI; ++mi)
#pragma unroll
            for (int ni = 0; ni < NI; ++ni)
#pragma unroll
                for (int r = 0; r < 4; ++r) {
                    int grow = m0 + wrow + mi * 16 + g * 4 + r;
                    int gcol = n0 + wcol + ni * 16 + t;
                    float v = acc[mi][ni][r];
                    if (MODE == 1) {
                        size_t idx = (size_t)grow * Dc + gcol;
                        outf[idx] = xres[idx] + v;
                    } else {
                        int c = gcol - region * 768;
                        int h = c >> 6, kd = c & 63;
                        int b = grow >> 11, ti = grow & (Tc - 1);
                        if (region == 0)
                            qb[((size_t)(b * Hc + h) * Tc + ti) * 64 + kd] = (__bf16)v;
                        else if (region == 1) {
                            int kds = kd ^ ((ti & 7) << 3);
                            kbf[((size_t)(b * Hc + h) * Tc + ti) * 64 + kds] = (__bf16)v;
                        } else
                            qgb[((size_t)(b * Hc + h) * Tc + ti) * 64 + kd] = (__bf16)fmaxf(v, 0.f);
                    }
                }
    }
}

// ---------------- sliding-window attention + fused GDN retrieval ----------------
// grid 768 (XCD-swizzled); 8 waves: wave-groups {0-3},{4-7} own the SAME 64
// q-rows, even/odd 64-key tiles (fixed-max softmax -> no sequential dep).
__global__ __launch_bounds__(512, 6) void k_attn(
    const __bf16* __restrict__ q, const __bf16* __restrict__ k,
    const __bf16* __restrict__ vt, const __bf16* __restrict__ qg,
    const __bf16* __restrict__ stateT, const float* __restrict__ gmean,
    __bf16* __restrict__ ac)
{
    __shared__ __bf16 Ks[3][64 * 64];
    __shared__ __bf16 Vs[3][64 * 64];
    int id = blockIdx.x, xcd = id & 7, l = id >> 3;
    int nid = xcd * 96 + l;
    int sblk = nid & 31, h = (nid >> 5) % Hc, b = nid / (32 * Hc);
    int tid = threadIdx.x;
    int w = tid >> 6, lane = tid & 63;
    int g = lane >> 4, t = lane & 15;
    int q0 = sblk * 64, qw = q0 + (w & 3) * 16;
    const int myPar = w >> 2;
    const __bf16* qb = q + (size_t)(b * Hc + h) * Tc * 64;
    const __bf16* kb = k + (size_t)(b * Hc + h) * Tc * 64;
    const __bf16* vb = vt + (size_t)(b * Hc + h) * 64 * Tc;

    bf16x8 qf0 = *(const bf16x8*)(qb + (size_t)(qw + t) * 64 + g * 8);
    bf16x8 qf1 = *(const bf16x8*)(qb + (size_t)(qw + t) * 64 + 32 + g * 8);

    const int qi = qw + t;
    const int lowB = qi - Wc;
    const int xr = t & 7;

    f32x4 oacc[4] = {};
    float lsum = 0.f;

    const int s_begin = (q0 >= Wc) ? q0 - Wc : 0;
    const int NT = (q0 + 64 - s_begin) >> 6;

    auto STAGE = [&](int buf, int s0) {
        int ch = tid;
        gload16(kb + (size_t)(s0 + (ch >> 3)) * 64 + (ch & 7) * 8, &Ks[buf][ch * 8]);
        gload16(vb + (size_t)(ch >> 3) * Tc + s0 + (ch & 7) * 8, &Vs[buf][ch * 8]);
    };

    STAGE(0, s_begin);
    if (NT > 1) STAGE(1, s_begin + 64);
    if (NT > 2) STAGE(2, s_begin + 128);
    int buf = 0;
    for (int it = 0; it < NT; ++it) {
        int s0 = s_begin + it * 64;
        wait_tiles2(NT - 1 - it);
        bar();
        if ((it & 1) == myPar) {
            const __bf16* Kt = Ks[buf];
            const __bf16* Vt = Vs[buf];
            f32x4 sc[4];
            __builtin_amdgcn_s_setprio(1);
#pragma unroll
            for (int sub = 0; sub < 4; ++sub) {
                const __bf16* kr = Kt + (sub * 16 + t) * 64;
                bf16x8 kA = *(const bf16x8*)(kr + ((g ^ xr) << 3));
                bf16x8 kB = *(const bf16x8*)(kr + (((g + 4) ^ xr) << 3));
                f32x4 s = {};
                s = mfma_bf16(kA, qf0, s);
                s = mfma_bf16(kB, qf1, s);
                sc[sub] = s;
            }
            __builtin_amdgcn_s_setprio(0);
            float pv[4][4];
            bool fullT = (s0 + 63 <= qw) && (s0 >= qw + 15 - Wc);
            if (fullT) {
#pragma unroll
                for (int sub = 0; sub < 4; ++sub)
#pragma unroll
                    for (int r = 0; r < 4; ++r) {
                        float e = exp2f(sc[sub][r]);
                        pv[sub][r] = e;
                        lsum += e;
                    }
            } else {
#pragma unroll
                for (int sub = 0; sub < 4; ++sub)
#pragma unroll
                    for (int r = 0; r < 4; ++r) {
                        int kk = s0 + sub * 16 + g * 4 + r;
                        float e = exp2f(sc[sub][r]);
                        float val = (kk <= qi && kk >= lowB) ? e : 0.f;
                        pv[sub][r] = val;
                        lsum += val;
                    }
            }
            __builtin_amdgcn_s_setprio(1);
#pragma unroll
            for (int ks = 0; ks < 2; ++ks) {
                union { uint32_t u[4]; bf16x8 v; } pf;
                pf.u[0] = pack2(pv[ks * 2][0], pv[ks * 2][1]);
                pf.u[1] = pack2(pv[ks * 2][2], pv[ks * 2][3]);
                pf.u[2] = pack2(pv[ks * 2 + 1][0], pv[ks * 2 + 1][1]);
                pf.u[3] = pack2(pv[ks * 2 + 1][2], pv[ks * 2 + 1][3]);
#pragma unroll
                for (int n = 0; n < 4; ++n) {
                    const __bf16* vrow = Vt + (n * 16 + t) * 64;
                    bf16x8 vf = *(const bf16x8*)(vrow + ((((ks * 4) + g) ^ xr) << 3));
                    oacc[n] = mfma_bf16(pf.v, vf, oacc[n]);
                }
            }
            __builtin_amdgcn_s_setprio(0);
        }
        s_wait_lgkm0();
        __builtin_amdgcn_sched_barrier(0);
        bar();
        if (it + 3 < NT) STAGE(buf, s0 + 192);
        buf = (buf == 2) ? 0 : buf + 1;
    }
    float* cb = (float*)&Ks[0][0];
    if (w >= 4) {
        float* dst = cb + ((size_t)((w - 4) * 64 + lane)) * 20;
#pragma unroll
        for (int n = 0; n < 4; ++n) *(f32x4*)(dst + n * 4) = oacc[n];
        dst[16] = lsum;
    }
    bar();
    if (w < 4) {
        const float* src = cb + ((size_t)(w * 64 + lane)) * 20;
#pragma unroll
        for (int n = 0; n < 4; ++n) oacc[n] += *(const f32x4*)(src + n * 4);
        lsum += src[16];
        lsum += __shfl_xor(lsum, 16, 64);
        lsum += __shfl_xor(lsum, 32, 64);
        float linv = 1.f / lsum;
        float lq[4];
#pragma unroll
        for (int r = 0; r < 4; ++r) lq[r] = __shfl(linv, g * 4 + r, 64);
#pragma unroll
        for (int n = 0; n < 4; ++n)
#pragma unroll
            for (int r = 0; r < 4; ++r) {
                int qrow = qw + g * 4 + r;
                ac[(size_t)(b * Tc + qrow) * 1536 + h * 64 + n * 16 + t] =
                    (__bf16)(oacc[n][r] * lq[r]);
            }
        const __bf16* qgp = qg + (size_t)(b * Hc + h) * Tc * 64;
        const __bf16* sb = stateT + (size_t)(b * Hc + h) * 4096;
        bf16x8 a0 = *(const bf16x8*)(qgp + (size_t)(qw + t) * 64 + g * 8);
        bf16x8 a1 = *(const bf16x8*)(qgp + (size_t)(qw + t) * 64 + 32 + g * 8);
#pragma unroll
        for (int n = 0; n < 4; ++n) {
            bf16x8 b0 = *(const bf16x8*)(sb + (n * 16 + t) * 64 + g * 8);
            bf16x8 b1 = *(const bf16x8*)(sb + (n * 16 + t) * 64 + 32 + g * 8);
            f32x4 acc2 = {};
            acc2 = mfma_bf16(a0, b0, acc2);
            acc2 = mfma_bf16(a1, b1, acc2);
#pragma unroll
            for (int r = 0; r < 4; ++r) {
                int ti = qw + g * 4 + r;
                float gm = gmean[b * Tc + ti];
                ac[(size_t)(b * Tc + ti) * 1536 + 768 + h * 64 + n * 16 + t] =
                    (__bf16)(acc2[r] * gm);
            }
        }
    }
}

// ---------------- host ----------------
extern "C" void kernel_launch(void* const* d_in, const int* in_sizes, int n_in,
                              void* d_out, int out_size, void* d_ws, size_t ws_size,
                              hipStream_t stream) {
    (void)in_sizes; (void)n_in; (void)out_size; (void)ws_size;
    const float* x     = (const float*)d_in[0];
    const float* gdn   = (const float*)d_in[1];
    const float* Wq    = (const float*)d_in[2];
    const float* Wk    = (const float*)d_in[3];
    const float* Wv    = (const float*)d_in[4];
    const float* Wo    = (const float*)d_in[5];
    const float* Wgq   = (const float*)d_in[6];
    const float* Wro   = (const float*)d_in[7];
    const float* Wg    = (const float*)d_in[8];
    const float* bg    = (const float*)d_in[9];
    const float* normw = (const float*)d_in[10];
    float* out = (float*)d_out;

    char* p = (char*)d_ws;
    auto alloc = [&](size_t bytes) -> char* {
        char* r = p; p += (bytes + 255) & ~(size_t)255; return r;
    };
    constexpr size_t NROW = (size_t)Bc * Tc;          // 4096
    __bf16* xnb    = (__bf16*)alloc(NROW * Dc * 2);
    __bf16* wTproj = (__bf16*)alloc((size_t)4 * Dc * Dc * 2);   // 3072 x 768
    __bf16* wTout  = (__bf16*)alloc((size_t)Dc * 1536 * 2);     // 768 x 1536
    __bf16* stT    = (__bf16*)alloc((size_t)Bc * Hc * 64 * 64 * 2);
    __bf16* qbuf   = (__bf16*)alloc(NROW * Dc * 2);
    __bf16* kbuf   = (__bf16*)alloc(NROW * Dc * 2);
    __bf16* qgbuf  = (__bf16*)alloc(NROW * Dc * 2);
    __bf16* vtbuf  = (__bf16*)alloc(NROW * Dc * 2);
    __bf16* ac     = (__bf16*)alloc(NROW * 1536 * 2);           // [local | retr]
    float*  gmean  = (float*)alloc(NROW * 4);

    k_prep_w<<<dim3(144, 6), 256, 0, stream>>>(Wq, Wk, Wv, Wgq, Wo, Wro, wTproj, wTout);
    k_prep_state<<<(Bc * Hc * 64 * 64) / 256, 256, 0, stream>>>(gdn, stT);
    k_norm_gate<<<NROW, 256, 0, stream>>>(x, normw, Wg, bg, xnb, gmean);

    k_gemm<0><<<768, 256, 0, stream>>>(xnb, wTproj, nullptr, nullptr,
                                       qbuf, kbuf, vtbuf, qgbuf);
    k_attn<<<768, 512, 0, stream>>>(qbuf, kbuf, vtbuf, qgbuf, stT, gmean, ac);
    k_gemm<1><<<768, 256, 0, stream>>>(ac, wTout, x, out,
                                       nullptr, nullptr, nullptr, nullptr);
}